// Round 7
// baseline (925.055 us; speedup 1.0000x reference)
//
#include <hip/hip_runtime.h>

// Problem constants (from reference)
#define N_C 50000
#define N_V 100000
#define N_A 5000
#define E_C2V 1600000
#define E_A2V 1000000
#define D_V 13
#define D_C 14
#define D_A 14
#define EMB 32

// h[j] += v * Wrow[j]; Wrow wave-uniform -> scalar loads.
__device__ __forceinline__ void accrow(float* __restrict__ h, float v,
                                       const float* __restrict__ Wrow) {
#pragma unroll
  for (int j = 0; j < EMB; ++j) h[j] = fmaf(v, Wrow[j], h[j]);
}

// -------- merged degree histograms (one pass over the big edge range)
__global__ __launch_bounds__(256) void k_counts(
    const int* __restrict__ c2v_t, const int* __restrict__ a2v_t,
    const int* __restrict__ a2v_s, int* __restrict__ deg_g,
    int* __restrict__ deg_h, int* __restrict__ deg_a) {
  int e = blockIdx.x * blockDim.x + threadIdx.x;
  if (e < E_C2V) atomicAdd(&deg_g[c2v_t[e]], 1);
  if (e < E_A2V) {
    atomicAdd(&deg_h[a2v_t[e]], 1);
    atomicAdd(&deg_a[a2v_s[e]], 1);
  }
}

// -------- merged slot allocation: block-range selects side.
#define NBV ((N_V + 255) / 256)  // 391
#define NBA ((N_A + 255) / 256)  // 20
__global__ __launch_bounds__(256) void k_allocs(
    const int* __restrict__ deg_g, int* __restrict__ off_g, int* __restrict__ head_g,
    const int* __restrict__ deg_h, int* __restrict__ off_h, int* __restrict__ head_h,
    const int* __restrict__ deg_a, int* __restrict__ off_a, int* __restrict__ head_a,
    int* __restrict__ ctr) {
  const int* deg;
  int* off;
  int* head;
  int* c;
  int i, n;
  if (blockIdx.x < NBV) {
    i = blockIdx.x * 256 + threadIdx.x;
    deg = deg_g; off = off_g; head = head_g; c = ctr + 0; n = N_V;
  } else if (blockIdx.x < 2 * NBV) {
    i = (blockIdx.x - NBV) * 256 + threadIdx.x;
    deg = deg_h; off = off_h; head = head_h; c = ctr + 1; n = N_V;
  } else {
    i = (blockIdx.x - 2 * NBV) * 256 + threadIdx.x;
    deg = deg_a; off = off_a; head = head_a; c = ctr + 2; n = N_A;
  }
  int lane = threadIdx.x & 63;
  int d = (i < n) ? deg[i] : 0;
  int v = d;  // inclusive wave scan
#pragma unroll
  for (int s = 1; s < 64; s <<= 1) {
    int t = __shfl_up(v, s, 64);
    if (lane >= s) v += t;
  }
  int total = __shfl(v, 63, 64);
  int base = 0;
  if (lane == 63) base = atomicAdd(c, total);
  base = __shfl(base, 63, 64);
  if (i < n) {
    int o = base + v - d;
    off[i] = o;
    head[i] = o;
  }
}

// -------- merged CSR fill for ALL three sides (perm only; nid recomputed
// later as tgt[e] — halves the scattered write payload vs perm+nid).
__global__ __launch_bounds__(256) void k_fill_all(
    const int* __restrict__ c2v_t, int* __restrict__ head_g,
    int* __restrict__ perm_g,
    const int* __restrict__ a2v_t, int* __restrict__ head_h,
    int* __restrict__ perm_h,
    const int* __restrict__ a2v_s, int* __restrict__ head_a,
    int* __restrict__ perm_a) {
  int e = blockIdx.x * blockDim.x + threadIdx.x;
  if (e < E_C2V) {
    int pos = atomicAdd(&head_g[c2v_t[e]], 1);
    perm_g[pos] = e;
  }
  if (e < E_A2V) {
    int pos = atomicAdd(&head_h[a2v_t[e]], 1);
    perm_h[pos] = e;
    int pos2 = atomicAdd(&head_a[a2v_s[e]], 1);
    perm_a[pos2] = e;
  }
}

// -------- edge-parallel v-side edge MLP (FIN=28) + per-wave segmented
// reduction + mean-scale + projection through the f_v W1 slice -> hacc.
// lane = CSR slot (edges grouped by dest v); t recomputed as tgt[e].
__global__ __launch_bounds__(256) void k_edge_v(
    int E,
    const int* __restrict__ perm, const int* __restrict__ tgt,
    const int* __restrict__ srcv,
    const float* __restrict__ x_t,   // variable-node feats (13)
    const float* __restrict__ x_s,   // source feats (14)
    const float* __restrict__ ea,    // 1 per edge
    const float* __restrict__ W1, const float* __restrict__ b1,
    const float* __restrict__ W2, const float* __restrict__ b2,
    const float* __restrict__ Wp,    // fW1 + (13 or 45)*32: projection slice
    const int* __restrict__ deg,
    float* __restrict__ hacc) {
  __shared__ float vals[4][64][33];  // +1 pad: scan reads conflict-free
  __shared__ int nidl[4][64];
  __shared__ float segx[4][32];
  int wv = threadIdx.x >> 6;
  int lane = threadIdx.x & 63;
  int slot = blockIdx.x * 256 + threadIdx.x;
  if ((slot & ~63) >= E) return;  // wave-uniform exit (E % 64 == 0)

  int e = perm[slot];
  int t = tgt[e];
  float eav = ea[e];
  int s = srcv[e];
  const float* xt = x_t + (size_t)t * D_V;

  float h[EMB];
#pragma unroll
  for (int j = 0; j < EMB; ++j) h[j] = b1[j];
#pragma unroll
  for (int i = 0; i < D_V; ++i) accrow(h, xt[i], W1 + i * EMB);
  // 14-dim source row: 56 B, 8 B aligned -> float2 x7
  const float2* xs2 = (const float2*)(x_s + (size_t)s * D_C);
#pragma unroll
  for (int i = 0; i < 7; ++i) {
    float2 w = xs2[i];
    accrow(h, w.x, W1 + (D_V + 2 * i) * EMB);
    accrow(h, w.y, W1 + (D_V + 2 * i + 1) * EMB);
  }
  accrow(h, eav, W1 + 27 * EMB);
#pragma unroll
  for (int j = 0; j < EMB; ++j) h[j] = fmaxf(h[j], 0.0f);
  // second layer, one output channel at a time (W2 index wave-uniform)
#pragma unroll
  for (int j = 0; j < EMB; ++j) {
    float o = b2[j];
#pragma unroll
    for (int k = 0; k < EMB; ++k) o = fmaf(h[k], W2[k * EMB + j], o);
    vals[wv][lane][j] = fmaxf(o, 0.0f);
  }
  nidl[wv][lane] = t;
  // wave-synchronous from here (DS ops in-order within a wave)
  if (lane < EMB) {
    int j = lane;
    float acc = 0.0f;
    for (int r = 0; r < 64; ++r) {
      acc += vals[wv][r][j];
      int cur = nidl[wv][r];
      bool flush = (r == 63) || (nidl[wv][r + 1] != cur);
      if (flush) {  // wave-uniform branch (same for all 32 lanes)
        float inv = 1.0f / fmaxf((float)deg[cur], 1.0f);
        segx[wv][j] = acc * inv;
        float out = 0.0f;
#pragma unroll
        for (int k = 0; k < EMB; ++k)
          out = fmaf(segx[wv][k], Wp[k * EMB + j], out);
        atomicAdd(&hacc[(size_t)cur * EMB + j], out);
        acc = 0.0f;
      }
    }
  }
}

// -------- edge-parallel a-side g_a MLP (FIN=47: [xa(14), fv(32), ea(1)])
// + segmented reduce + projection through fa_W1[14:46] -> hacc_a.
__global__ __launch_bounds__(256) void k_edge_a(
    const int* __restrict__ perm,
    const int* __restrict__ a2v_s, const int* __restrict__ a2v_t,
    const float* __restrict__ xa_g, const float* __restrict__ fv,
    const float* __restrict__ ea,
    const float* __restrict__ W1, const float* __restrict__ b1,
    const float* __restrict__ W2, const float* __restrict__ b2,
    const float* __restrict__ Wp,   // fa_W1 + 14*32
    const int* __restrict__ deg,
    float* __restrict__ hacc_a) {
  __shared__ float vals[4][64][33];
  __shared__ int nidl[4][64];
  __shared__ float segx[4][32];
  int wv = threadIdx.x >> 6;
  int lane = threadIdx.x & 63;
  int slot = blockIdx.x * 256 + threadIdx.x;
  if ((slot & ~63) >= E_A2V) return;

  int e = perm[slot];
  int a = a2v_s[e];
  int t = a2v_t[e];
  float eav = ea[e];

  float h[EMB];
#pragma unroll
  for (int j = 0; j < EMB; ++j) h[j] = b1[j];
  const float2* ps2 = (const float2*)(xa_g + (size_t)a * D_A);
#pragma unroll
  for (int i = 0; i < 7; ++i) {
    float2 w = ps2[i];
    accrow(h, w.x, W1 + (2 * i) * EMB);
    accrow(h, w.y, W1 + (2 * i + 1) * EMB);
  }
  // fv row: 128 B, 16 B aligned -> float4 x8
  const float4* pf = (const float4*)(fv + (size_t)t * EMB);
#pragma unroll
  for (int q = 0; q < 8; ++q) {
    float4 f = pf[q];
    accrow(h, f.x, W1 + (D_A + 4 * q) * EMB);
    accrow(h, f.y, W1 + (D_A + 4 * q + 1) * EMB);
    accrow(h, f.z, W1 + (D_A + 4 * q + 2) * EMB);
    accrow(h, f.w, W1 + (D_A + 4 * q + 3) * EMB);
  }
  accrow(h, eav, W1 + 46 * EMB);
#pragma unroll
  for (int j = 0; j < EMB; ++j) h[j] = fmaxf(h[j], 0.0f);
#pragma unroll
  for (int j = 0; j < EMB; ++j) {
    float o = b2[j];
#pragma unroll
    for (int k = 0; k < EMB; ++k) o = fmaf(h[k], W2[k * EMB + j], o);
    vals[wv][lane][j] = fmaxf(o, 0.0f);
  }
  nidl[wv][lane] = a;
  if (lane < EMB) {
    int j = lane;
    float acc = 0.0f;
    for (int r = 0; r < 64; ++r) {
      acc += vals[wv][r][j];
      int cur = nidl[wv][r];
      bool flush = (r == 63) || (nidl[wv][r + 1] != cur);
      if (flush) {
        float inv = 1.0f / fmaxf((float)deg[cur], 1.0f);
        segx[wv][j] = acc * inv;
        float out = 0.0f;
#pragma unroll
        for (int k = 0; k < EMB; ++k)
          out = fmaf(segx[wv][k], Wp[k * EMB + j], out);
        atomicAdd(&hacc_a[(size_t)cur * EMB + j], out);
        acc = 0.0f;
      }
    }
  }
}

// -------- f_v node MLP on pre-accumulated hidden: thread per node.
__global__ __launch_bounds__(256) void k_node_fv(
    const float* __restrict__ xv_g, const float* __restrict__ hacc,
    const float* __restrict__ fW1, const float* __restrict__ fb1,
    const float* __restrict__ fW2, const float* __restrict__ fb2,
    float* __restrict__ fv_out) {
  int v = blockIdx.x * blockDim.x + threadIdx.x;
  if (v >= N_V) return;
  const float* hr = hacc + (size_t)v * EMB;
  float h[EMB];
#pragma unroll
  for (int j = 0; j < EMB; ++j) h[j] = fb1[j] + hr[j];
  const float* pv = xv_g + (size_t)v * D_V;
#pragma unroll
  for (int i = 0; i < D_V; ++i) accrow(h, pv[i], fW1 + i * EMB);
#pragma unroll
  for (int j = 0; j < EMB; ++j) h[j] = fmaxf(h[j], 0.0f);
  float* dst = fv_out + (size_t)v * EMB;
#pragma unroll
  for (int j = 0; j < EMB; ++j) {
    float o = fb2[j];
#pragma unroll
    for (int k = 0; k < EMB; ++k) o = fmaf(h[k], fW2[k * EMB + j], o);
    dst[j] = fmaxf(o, 0.0f);  // relu_out + reference's extra relu (idempotent)
  }
}

// -------- f_a node MLP on pre-accumulated hidden -> d_out
__global__ __launch_bounds__(256) void k_node_fa(
    const float* __restrict__ xa, const float* __restrict__ hacc_a,
    const float* __restrict__ W1, const float* __restrict__ b1,
    const float* __restrict__ W2, const float* __restrict__ b2,
    float* __restrict__ out) {
  int a = blockIdx.x * blockDim.x + threadIdx.x;
  if (a >= N_A) return;
  const float* hr = hacc_a + (size_t)a * EMB;
  float h[EMB];
#pragma unroll
  for (int j = 0; j < EMB; ++j) h[j] = b1[j] + hr[j];
  const float* pa = xa + (size_t)a * D_A;
#pragma unroll
  for (int i = 0; i < D_A; ++i) accrow(h, pa[i], W1 + i * EMB);
#pragma unroll
  for (int j = 0; j < EMB; ++j) h[j] = fmaxf(h[j], 0.0f);
  float* dst = out + (size_t)a * EMB;
#pragma unroll
  for (int j = 0; j < EMB; ++j) {
    float o = b2[j];
#pragma unroll
    for (int k = 0; k < EMB; ++k) o = fmaf(h[k], W2[k * EMB + j], o);
    dst[j] = fmaxf(o, 0.0f);
  }
}

extern "C" void kernel_launch(void* const* d_in, const int* in_sizes, int n_in,
                              void* d_out, int out_size, void* d_ws, size_t ws_size,
                              hipStream_t stream) {
  const float* x_c = (const float*)d_in[0];
  const float* x_v = (const float*)d_in[1];
  const float* x_a = (const float*)d_in[2];
  const int* c2v_s = (const int*)d_in[3];
  const int* c2v_t = (const int*)d_in[4];
  const int* a2v_s = (const int*)d_in[5];
  const int* a2v_t = (const int*)d_in[6];
  const float* ea_c2v = (const float*)d_in[7];
  const float* ea_a2v = (const float*)d_in[8];
  const float* gv_W1 = (const float*)d_in[9];
  const float* gv_b1 = (const float*)d_in[10];
  const float* gv_W2 = (const float*)d_in[11];
  const float* gv_b2 = (const float*)d_in[12];
  const float* hv_W1 = (const float*)d_in[13];
  const float* hv_b1 = (const float*)d_in[14];
  const float* hv_W2 = (const float*)d_in[15];
  const float* hv_b2 = (const float*)d_in[16];
  const float* fv_W1 = (const float*)d_in[17];
  const float* fv_b1 = (const float*)d_in[18];
  const float* fv_W2 = (const float*)d_in[19];
  const float* fv_b2 = (const float*)d_in[20];
  const float* ga_W1 = (const float*)d_in[21];
  const float* ga_b1 = (const float*)d_in[22];
  const float* ga_W2 = (const float*)d_in[23];
  const float* ga_b2 = (const float*)d_in[24];
  const float* fa_W1 = (const float*)d_in[25];
  const float* fa_b1 = (const float*)d_in[26];
  const float* fa_W2 = (const float*)d_in[27];
  const float* fa_b2 = (const float*)d_in[28];

  // ---- workspace layout: ~32.7 MB (proven envelope ~39 MB) ----
  // Region A: CSR ints (615,004 ints = 2.46 MB) -- zeroed (with C) below
  int* ip = (int*)d_ws;
  int* deg_g = ip;                  // 100000
  int* deg_h = deg_g + N_V;         // 100000
  int* deg_a = deg_h + N_V;         // 5000
  int* ctr = deg_a + N_A;           // 4
  int* off_g = ctr + 4;             // 100000
  int* off_h = off_g + N_V;         // 100000
  int* off_a = off_h + N_V;         // 5000
  int* head_g = off_a + N_A;        // 100000
  int* head_h = head_g + N_V;       // 100000
  int* head_a = head_h + N_V;       // 5000
  // Region C (contiguous with A for a single memset): hacc + hacc_a
  float* hacc = (float*)(head_a + N_A);         // N_V*32 floats
  float* hacc_a = hacc + (size_t)N_V * EMB;     // N_A*32 floats
  // Region B: 3.2M ints (12.8 MB), time-multiplexed:
  //   phase 1: perm_g(1.6M) + perm_h(1.0M)  [fill_all .. edge_h]
  //   phase 2: fv (3.2M floats)             [node_fv .. edge_a]
  int* B = (int*)(hacc_a + (size_t)N_A * EMB);
  int* perm_g = B;
  int* perm_h = B + E_C2V;
  float* fv = (float*)B;
  // Region D: perm_a (1.0M ints = 4 MB), lifetime fill_all .. edge_a
  int* perm_a = B + 2 * E_C2V;  // note: B region is 3.2M ints; perm_a after

  // one memset: A (deg/ctr/off/head) + C (hacc, hacc_a)
  hipMemsetAsync(d_ws, 0,
                 (size_t)(615004) * sizeof(int) +
                     (size_t)(N_V + N_A) * EMB * sizeof(float),
                 stream);

  // degrees (one pass) + offsets (one launch, block-range per side)
  k_counts<<<(E_C2V + 255) / 256, 256, 0, stream>>>(c2v_t, a2v_t, a2v_s,
                                                    deg_g, deg_h, deg_a);
  k_allocs<<<2 * NBV + NBA, 256, 0, stream>>>(deg_g, off_g, head_g,
                                              deg_h, off_h, head_h,
                                              deg_a, off_a, head_a, ctr);
  // CSR fill: all three perms in one pass
  k_fill_all<<<(E_C2V + 255) / 256, 256, 0, stream>>>(
      c2v_t, head_g, perm_g, a2v_t, head_h, perm_h, a2v_s, head_a, perm_a);
  // g side edge MLP + reduce -> hacc
  k_edge_v<<<E_C2V / 256, 256, 0, stream>>>(
      E_C2V, perm_g, c2v_t, c2v_s, x_v, x_c, ea_c2v,
      gv_W1, gv_b1, gv_W2, gv_b2, fv_W1 + (size_t)D_V * EMB, deg_g, hacc);
  // h side edge MLP + reduce -> hacc
  k_edge_v<<<(E_A2V + 255) / 256, 256, 0, stream>>>(
      E_A2V, perm_h, a2v_t, a2v_s, x_v, x_a, ea_a2v,
      hv_W1, hv_b1, hv_W2, hv_b2, fv_W1 + (size_t)(D_V + EMB) * EMB, deg_h, hacc);
  // f_v from hacc; fv lands in B (perm_g/perm_h dead)
  k_node_fv<<<(N_V + 255) / 256, 256, 0, stream>>>(
      x_v, hacc, fv_W1, fv_b1, fv_W2, fv_b2, fv);
  // a side edge MLP + reduce -> hacc_a
  k_edge_a<<<(E_A2V + 255) / 256, 256, 0, stream>>>(
      perm_a, a2v_s, a2v_t, x_a, fv, ea_a2v,
      ga_W1, ga_b1, ga_W2, ga_b2, fa_W1 + (size_t)D_A * EMB, deg_a, hacc_a);
  // f_a -> out
  k_node_fa<<<(N_A + 255) / 256, 256, 0, stream>>>(
      x_a, hacc_a, fa_W1, fa_b1, fa_W2, fa_b2, (float*)d_out);
}

// Round 8
// 864.502 us; speedup vs baseline: 1.0700x; 1.0700x over previous
//
#include <hip/hip_runtime.h>

// Problem constants (from reference)
#define N_C 50000
#define N_V 100000
#define N_A 5000
#define E_C2V 1600000
#define E_A2V 1000000
#define D_V 13
#define D_C 14
#define D_A 14
#define EMB 32

// Residue-major node-index permutation: nodes with the same (id & 7) are
// contiguous, so every deg/head/perm-range cache line is owned by the one
// XCD that processes that residue (blockIdx&7 == XCD under round-robin).
#define PV(t) (((t) >> 3) + ((t)&7) * (N_V / 8))  // N_V/8 = 12500
#define PA(t) (((t) >> 3) + ((t)&7) * (N_A / 8))  // N_A/8 = 625
#define NCH (E_C2V / 256)                         // 6250 chunks, exact

// h[j] += v * Wrow[j]; Wrow wave-uniform -> scalar loads.
__device__ __forceinline__ void accrow(float* __restrict__ h, float v,
                                       const float* __restrict__ Wrow) {
#pragma unroll
  for (int j = 0; j < EMB; ++j) h[j] = fmaf(v, Wrow[j], h[j]);
}

// -------- XCD-partitioned degree histograms.
// Block (chunk, res=blockIdx&7) counts only keys with (key&7)==res, into
// residue-major deg arrays: atomics + lines stay XCD-local.
__global__ __launch_bounds__(256) void k_counts(
    const int* __restrict__ c2v_t, const int* __restrict__ a2v_t,
    const int* __restrict__ a2v_s, int* __restrict__ deg_g,
    int* __restrict__ deg_h, int* __restrict__ deg_a) {
  int res = blockIdx.x & 7;
  int e = (blockIdx.x >> 3) * 256 + threadIdx.x;
  int t = c2v_t[e];  // e < E_C2V always (exact chunking)
  if ((t & 7) == res) atomicAdd(&deg_g[PV(t)], 1);
  if (e < E_A2V) {
    int th = a2v_t[e];
    if ((th & 7) == res) atomicAdd(&deg_h[PV(th)], 1);
    int ta = a2v_s[e];
    if ((ta & 7) == res) atomicAdd(&deg_a[PA(ta)], 1);
  }
}

// -------- merged slot allocation (order-agnostic: any disjoint ranges).
#define NBV ((N_V + 255) / 256)  // 391
#define NBA ((N_A + 255) / 256)  // 20
__global__ __launch_bounds__(256) void k_allocs(
    const int* __restrict__ deg_g, int* __restrict__ off_g, int* __restrict__ head_g,
    const int* __restrict__ deg_h, int* __restrict__ off_h, int* __restrict__ head_h,
    const int* __restrict__ deg_a, int* __restrict__ off_a, int* __restrict__ head_a,
    int* __restrict__ ctr) {
  const int* deg;
  int* off;
  int* head;
  int* c;
  int i, n;
  if (blockIdx.x < NBV) {
    i = blockIdx.x * 256 + threadIdx.x;
    deg = deg_g; off = off_g; head = head_g; c = ctr + 0; n = N_V;
  } else if (blockIdx.x < 2 * NBV) {
    i = (blockIdx.x - NBV) * 256 + threadIdx.x;
    deg = deg_h; off = off_h; head = head_h; c = ctr + 1; n = N_V;
  } else {
    i = (blockIdx.x - 2 * NBV) * 256 + threadIdx.x;
    deg = deg_a; off = off_a; head = head_a; c = ctr + 2; n = N_A;
  }
  int lane = threadIdx.x & 63;
  int d = (i < n) ? deg[i] : 0;
  int v = d;  // inclusive wave scan
#pragma unroll
  for (int s = 1; s < 64; s <<= 1) {
    int t = __shfl_up(v, s, 64);
    if (lane >= s) v += t;
  }
  int total = __shfl(v, 63, 64);
  int base = 0;
  if (lane == 63) base = atomicAdd(c, total);
  base = __shfl(base, 63, 64);
  if (i < n) {
    int o = base + v - d;
    off[i] = o;
    head[i] = o;
  }
}

// -------- XCD-partitioned CSR fill (same residue scheme as k_counts).
// perm slot ranges are residue-grouped (via residue-major off), so scatter
// lines are written by a single XCD and accumulate in its L2.
__global__ __launch_bounds__(256) void k_fill(
    const int* __restrict__ c2v_t, int* __restrict__ head_g,
    int* __restrict__ perm_g,
    const int* __restrict__ a2v_t, int* __restrict__ head_h,
    int* __restrict__ perm_h,
    const int* __restrict__ a2v_s, int* __restrict__ head_a,
    int* __restrict__ perm_a) {
  int res = blockIdx.x & 7;
  int e = (blockIdx.x >> 3) * 256 + threadIdx.x;
  int t = c2v_t[e];
  if ((t & 7) == res) {
    int pos = atomicAdd(&head_g[PV(t)], 1);
    perm_g[pos] = e;
  }
  if (e < E_A2V) {
    int th = a2v_t[e];
    if ((th & 7) == res) {
      int pos = atomicAdd(&head_h[PV(th)], 1);
      perm_h[pos] = e;
    }
    int ta = a2v_s[e];
    if ((ta & 7) == res) {
      int pos = atomicAdd(&head_a[PA(ta)], 1);
      perm_a[pos] = e;
    }
  }
}

// -------- edge-parallel v-side edge MLP (FIN=28) + per-wave segmented
// reduction + mean-scale + projection through the f_v W1 slice -> hacc.
__global__ __launch_bounds__(256) void k_edge_v(
    int E,
    const int* __restrict__ perm, const int* __restrict__ tgt,
    const int* __restrict__ srcv,
    const float* __restrict__ x_t,   // variable-node feats (13)
    const float* __restrict__ x_s,   // source feats (14)
    const float* __restrict__ ea,    // 1 per edge
    const float* __restrict__ W1, const float* __restrict__ b1,
    const float* __restrict__ W2, const float* __restrict__ b2,
    const float* __restrict__ Wp,    // fW1 + (13 or 45)*32: projection slice
    const int* __restrict__ deg,     // residue-major indexed
    float* __restrict__ hacc) {
  __shared__ float vals[4][64][33];  // +1 pad: scan reads conflict-free
  __shared__ int nidl[4][64];
  __shared__ float segx[4][32];
  int wv = threadIdx.x >> 6;
  int lane = threadIdx.x & 63;
  int slot = blockIdx.x * 256 + threadIdx.x;
  if ((slot & ~63) >= E) return;  // wave-uniform exit (E % 64 == 0)

  int e = perm[slot];
  int t = tgt[e];
  float eav = ea[e];
  int s = srcv[e];
  const float* xt = x_t + (size_t)t * D_V;

  float h[EMB];
#pragma unroll
  for (int j = 0; j < EMB; ++j) h[j] = b1[j];
#pragma unroll
  for (int i = 0; i < D_V; ++i) accrow(h, xt[i], W1 + i * EMB);
  // 14-dim source row: 56 B, 8 B aligned -> float2 x7
  const float2* xs2 = (const float2*)(x_s + (size_t)s * D_C);
#pragma unroll
  for (int i = 0; i < 7; ++i) {
    float2 w = xs2[i];
    accrow(h, w.x, W1 + (D_V + 2 * i) * EMB);
    accrow(h, w.y, W1 + (D_V + 2 * i + 1) * EMB);
  }
  accrow(h, eav, W1 + 27 * EMB);
#pragma unroll
  for (int j = 0; j < EMB; ++j) h[j] = fmaxf(h[j], 0.0f);
  // second layer, one output channel at a time (W2 index wave-uniform)
#pragma unroll
  for (int j = 0; j < EMB; ++j) {
    float o = b2[j];
#pragma unroll
    for (int k = 0; k < EMB; ++k) o = fmaf(h[k], W2[k * EMB + j], o);
    vals[wv][lane][j] = fmaxf(o, 0.0f);
  }
  nidl[wv][lane] = t;
  // wave-synchronous from here (DS ops in-order within a wave)
  if (lane < EMB) {
    int j = lane;
    float acc = 0.0f;
    for (int r = 0; r < 64; ++r) {
      acc += vals[wv][r][j];
      int cur = nidl[wv][r];
      bool flush = (r == 63) || (nidl[wv][r + 1] != cur);
      if (flush) {  // wave-uniform branch (same for all 32 lanes)
        float inv = 1.0f / fmaxf((float)deg[PV(cur)], 1.0f);
        segx[wv][j] = acc * inv;
        float out = 0.0f;
#pragma unroll
        for (int k = 0; k < EMB; ++k)
          out = fmaf(segx[wv][k], Wp[k * EMB + j], out);
        atomicAdd(&hacc[(size_t)cur * EMB + j], out);
        acc = 0.0f;
      }
    }
  }
}

// -------- edge-parallel a-side g_a MLP (FIN=47: [xa(14), fv(32), ea(1)])
// + segmented reduce + projection through fa_W1[14:46] -> hacc_a.
__global__ __launch_bounds__(256) void k_edge_a(
    const int* __restrict__ perm,
    const int* __restrict__ a2v_s, const int* __restrict__ a2v_t,
    const float* __restrict__ xa_g, const float* __restrict__ fv,
    const float* __restrict__ ea,
    const float* __restrict__ W1, const float* __restrict__ b1,
    const float* __restrict__ W2, const float* __restrict__ b2,
    const float* __restrict__ Wp,   // fa_W1 + 14*32
    const int* __restrict__ deg,    // residue-major indexed
    float* __restrict__ hacc_a) {
  __shared__ float vals[4][64][33];
  __shared__ int nidl[4][64];
  __shared__ float segx[4][32];
  int wv = threadIdx.x >> 6;
  int lane = threadIdx.x & 63;
  int slot = blockIdx.x * 256 + threadIdx.x;
  if ((slot & ~63) >= E_A2V) return;

  int e = perm[slot];
  int a = a2v_s[e];
  int t = a2v_t[e];
  float eav = ea[e];

  float h[EMB];
#pragma unroll
  for (int j = 0; j < EMB; ++j) h[j] = b1[j];
  const float2* ps2 = (const float2*)(xa_g + (size_t)a * D_A);
#pragma unroll
  for (int i = 0; i < 7; ++i) {
    float2 w = ps2[i];
    accrow(h, w.x, W1 + (2 * i) * EMB);
    accrow(h, w.y, W1 + (2 * i + 1) * EMB);
  }
  // fv row: 128 B, 16 B aligned -> float4 x8
  const float4* pf = (const float4*)(fv + (size_t)t * EMB);
#pragma unroll
  for (int q = 0; q < 8; ++q) {
    float4 f = pf[q];
    accrow(h, f.x, W1 + (D_A + 4 * q) * EMB);
    accrow(h, f.y, W1 + (D_A + 4 * q + 1) * EMB);
    accrow(h, f.z, W1 + (D_A + 4 * q + 2) * EMB);
    accrow(h, f.w, W1 + (D_A + 4 * q + 3) * EMB);
  }
  accrow(h, eav, W1 + 46 * EMB);
#pragma unroll
  for (int j = 0; j < EMB; ++j) h[j] = fmaxf(h[j], 0.0f);
#pragma unroll
  for (int j = 0; j < EMB; ++j) {
    float o = b2[j];
#pragma unroll
    for (int k = 0; k < EMB; ++k) o = fmaf(h[k], W2[k * EMB + j], o);
    vals[wv][lane][j] = fmaxf(o, 0.0f);
  }
  nidl[wv][lane] = a;
  if (lane < EMB) {
    int j = lane;
    float acc = 0.0f;
    for (int r = 0; r < 64; ++r) {
      acc += vals[wv][r][j];
      int cur = nidl[wv][r];
      bool flush = (r == 63) || (nidl[wv][r + 1] != cur);
      if (flush) {
        float inv = 1.0f / fmaxf((float)deg[PA(cur)], 1.0f);
        segx[wv][j] = acc * inv;
        float out = 0.0f;
#pragma unroll
        for (int k = 0; k < EMB; ++k)
          out = fmaf(segx[wv][k], Wp[k * EMB + j], out);
        atomicAdd(&hacc_a[(size_t)cur * EMB + j], out);
        acc = 0.0f;
      }
    }
  }
}

// -------- f_v node MLP on pre-accumulated hidden: thread per node.
__global__ __launch_bounds__(256) void k_node_fv(
    const float* __restrict__ xv_g, const float* __restrict__ hacc,
    const float* __restrict__ fW1, const float* __restrict__ fb1,
    const float* __restrict__ fW2, const float* __restrict__ fb2,
    float* __restrict__ fv_out) {
  int v = blockIdx.x * blockDim.x + threadIdx.x;
  if (v >= N_V) return;
  const float* hr = hacc + (size_t)v * EMB;
  float h[EMB];
#pragma unroll
  for (int j = 0; j < EMB; ++j) h[j] = fb1[j] + hr[j];
  const float* pv = xv_g + (size_t)v * D_V;
#pragma unroll
  for (int i = 0; i < D_V; ++i) accrow(h, pv[i], fW1 + i * EMB);
#pragma unroll
  for (int j = 0; j < EMB; ++j) h[j] = fmaxf(h[j], 0.0f);
  float* dst = fv_out + (size_t)v * EMB;
#pragma unroll
  for (int j = 0; j < EMB; ++j) {
    float o = fb2[j];
#pragma unroll
    for (int k = 0; k < EMB; ++k) o = fmaf(h[k], fW2[k * EMB + j], o);
    dst[j] = fmaxf(o, 0.0f);  // relu_out + reference's extra relu (idempotent)
  }
}

// -------- f_a node MLP on pre-accumulated hidden -> d_out
__global__ __launch_bounds__(256) void k_node_fa(
    const float* __restrict__ xa, const float* __restrict__ hacc_a,
    const float* __restrict__ W1, const float* __restrict__ b1,
    const float* __restrict__ W2, const float* __restrict__ b2,
    float* __restrict__ out) {
  int a = blockIdx.x * blockDim.x + threadIdx.x;
  if (a >= N_A) return;
  const float* hr = hacc_a + (size_t)a * EMB;
  float h[EMB];
#pragma unroll
  for (int j = 0; j < EMB; ++j) h[j] = b1[j] + hr[j];
  const float* pa = xa + (size_t)a * D_A;
#pragma unroll
  for (int i = 0; i < D_A; ++i) accrow(h, pa[i], W1 + i * EMB);
#pragma unroll
  for (int j = 0; j < EMB; ++j) h[j] = fmaxf(h[j], 0.0f);
  float* dst = out + (size_t)a * EMB;
#pragma unroll
  for (int j = 0; j < EMB; ++j) {
    float o = b2[j];
#pragma unroll
    for (int k = 0; k < EMB; ++k) o = fmaf(h[k], W2[k * EMB + j], o);
    dst[j] = fmaxf(o, 0.0f);
  }
}

extern "C" void kernel_launch(void* const* d_in, const int* in_sizes, int n_in,
                              void* d_out, int out_size, void* d_ws, size_t ws_size,
                              hipStream_t stream) {
  const float* x_c = (const float*)d_in[0];
  const float* x_v = (const float*)d_in[1];
  const float* x_a = (const float*)d_in[2];
  const int* c2v_s = (const int*)d_in[3];
  const int* c2v_t = (const int*)d_in[4];
  const int* a2v_s = (const int*)d_in[5];
  const int* a2v_t = (const int*)d_in[6];
  const float* ea_c2v = (const float*)d_in[7];
  const float* ea_a2v = (const float*)d_in[8];
  const float* gv_W1 = (const float*)d_in[9];
  const float* gv_b1 = (const float*)d_in[10];
  const float* gv_W2 = (const float*)d_in[11];
  const float* gv_b2 = (const float*)d_in[12];
  const float* hv_W1 = (const float*)d_in[13];
  const float* hv_b1 = (const float*)d_in[14];
  const float* hv_W2 = (const float*)d_in[15];
  const float* hv_b2 = (const float*)d_in[16];
  const float* fv_W1 = (const float*)d_in[17];
  const float* fv_b1 = (const float*)d_in[18];
  const float* fv_W2 = (const float*)d_in[19];
  const float* fv_b2 = (const float*)d_in[20];
  const float* ga_W1 = (const float*)d_in[21];
  const float* ga_b1 = (const float*)d_in[22];
  const float* ga_W2 = (const float*)d_in[23];
  const float* ga_b2 = (const float*)d_in[24];
  const float* fa_W1 = (const float*)d_in[25];
  const float* fa_b1 = (const float*)d_in[26];
  const float* fa_W2 = (const float*)d_in[27];
  const float* fa_b2 = (const float*)d_in[28];

  // ---- workspace layout: ~32.7 MB (proven envelope ~39 MB) ----
  // Region A: CSR ints (615,004 ints) -- residue-major indexed
  int* ip = (int*)d_ws;
  int* deg_g = ip;                  // 100000
  int* deg_h = deg_g + N_V;         // 100000
  int* deg_a = deg_h + N_V;         // 5000
  int* ctr = deg_a + N_A;           // 4
  int* off_g = ctr + 4;             // 100000
  int* off_h = off_g + N_V;         // 100000
  int* off_a = off_h + N_V;         // 5000
  int* head_g = off_a + N_A;        // 100000
  int* head_h = head_g + N_V;       // 100000
  int* head_a = head_h + N_V;       // 5000
  // Region C (contiguous with A for a single memset): hacc + hacc_a
  float* hacc = (float*)(head_a + N_A);         // N_V*32 floats
  float* hacc_a = hacc + (size_t)N_V * EMB;     // N_A*32 floats
  // Region B: 3.2M ints, time-multiplexed:
  //   phase 1: perm_g(1.6M) + perm_h(1.0M)  [fill .. edge_h]
  //   phase 2: fv (3.2M floats)             [node_fv .. edge_a]
  int* B = (int*)(hacc_a + (size_t)N_A * EMB);
  int* perm_g = B;
  int* perm_h = B + E_C2V;
  float* fv = (float*)B;
  // Region D: perm_a (1.0M ints), lifetime fill .. edge_a
  int* perm_a = B + 2 * E_C2V;

  // one memset: A (deg/ctr/off/head) + C (hacc, hacc_a)
  hipMemsetAsync(d_ws, 0,
                 (size_t)(615004) * sizeof(int) +
                     (size_t)(N_V + N_A) * EMB * sizeof(float),
                 stream);

  // XCD-partitioned degrees + fill (8 residues x 6250 chunks)
  k_counts<<<8 * NCH, 256, 0, stream>>>(c2v_t, a2v_t, a2v_s,
                                        deg_g, deg_h, deg_a);
  k_allocs<<<2 * NBV + NBA, 256, 0, stream>>>(deg_g, off_g, head_g,
                                              deg_h, off_h, head_h,
                                              deg_a, off_a, head_a, ctr);
  k_fill<<<8 * NCH, 256, 0, stream>>>(
      c2v_t, head_g, perm_g, a2v_t, head_h, perm_h, a2v_s, head_a, perm_a);
  // g side edge MLP + reduce -> hacc
  k_edge_v<<<E_C2V / 256, 256, 0, stream>>>(
      E_C2V, perm_g, c2v_t, c2v_s, x_v, x_c, ea_c2v,
      gv_W1, gv_b1, gv_W2, gv_b2, fv_W1 + (size_t)D_V * EMB, deg_g, hacc);
  // h side edge MLP + reduce -> hacc
  k_edge_v<<<(E_A2V + 255) / 256, 256, 0, stream>>>(
      E_A2V, perm_h, a2v_t, a2v_s, x_v, x_a, ea_a2v,
      hv_W1, hv_b1, hv_W2, hv_b2, fv_W1 + (size_t)(D_V + EMB) * EMB, deg_h, hacc);
  // f_v from hacc; fv lands in B (perm_g/perm_h dead)
  k_node_fv<<<(N_V + 255) / 256, 256, 0, stream>>>(
      x_v, hacc, fv_W1, fv_b1, fv_W2, fv_b2, fv);
  // a side edge MLP + reduce -> hacc_a
  k_edge_a<<<(E_A2V + 255) / 256, 256, 0, stream>>>(
      perm_a, a2v_s, a2v_t, x_a, fv, ea_a2v,
      ga_W1, ga_b1, ga_W2, ga_b2, fa_W1 + (size_t)D_A * EMB, deg_a, hacc_a);
  // f_a -> out
  k_node_fa<<<(N_A + 255) / 256, 256, 0, stream>>>(
      x_a, hacc_a, fa_W1, fa_b1, fa_W2, fa_b2, (float*)d_out);
}